// Round 8
// baseline (682.649 us; speedup 1.0000x reference)
//
#include <hip/hip_runtime.h>
#include <cstdint>
#include <cstddef>

#define N_NODES 100000
#define N_EDGES 1600000
#define FDIM 128
#define NCLS 40
#define SCAN_BLOCKS 98   // ceil(100000/1024)

// ---------------- degree count ----------------
__global__ void count_kernel(const int* __restrict__ dst, int* __restrict__ cnt, int E) {
    int e = blockIdx.x * blockDim.x + threadIdx.x;
    if (e < E) atomicAdd(&cnt[dst[e]], 1);
}

// ---------------- 3-phase exclusive scan over cnt -> csr_off (+ deg_inv) -------
__global__ void scan_phase1(const int* __restrict__ cnt, int* __restrict__ excl,
                            int* __restrict__ bsum, float* __restrict__ deg_inv, int n) {
    __shared__ int lds[1024];
    int tid = threadIdx.x;
    int i = blockIdx.x * 1024 + tid;
    int v = (i < n) ? cnt[i] : 0;
    if (i < n) deg_inv[i] = 1.0f / (float)(v + 1);   // +1 self loop
    lds[tid] = v;
    __syncthreads();
    for (int d = 1; d < 1024; d <<= 1) {
        int t = (tid >= d) ? lds[tid - d] : 0;
        __syncthreads();
        lds[tid] += t;
        __syncthreads();
    }
    if (i < n) excl[i] = lds[tid] - v;
    if (tid == 1023) bsum[blockIdx.x] = lds[1023];
}

__global__ void scan_phase2(const int* __restrict__ bsum, int* __restrict__ boff, int nb) {
    __shared__ int lds[128];
    int tid = threadIdx.x;   // blockDim = 128, nb <= 128
    int v = (tid < nb) ? bsum[tid] : 0;
    lds[tid] = v;
    __syncthreads();
    for (int d = 1; d < 128; d <<= 1) {
        int t = (tid >= d) ? lds[tid - d] : 0;
        __syncthreads();
        lds[tid] += t;
        __syncthreads();
    }
    if (tid < nb) boff[tid] = lds[tid] - v;
    if (tid == 127) boff[nb] = lds[127];   // grand total = E
}

__global__ void scan_phase3(const int* __restrict__ excl, const int* __restrict__ boff,
                            int* __restrict__ off, int n, int nb) {
    int i = blockIdx.x * blockDim.x + threadIdx.x;
    if (i < n) off[i] = excl[i] + boff[i >> 10];
    if (i == 0) off[n] = boff[nb];
}

// fill: consumes cnt via atomicSub (cnt not needed afterwards)
__global__ void fill_kernel(const int* __restrict__ src, const int* __restrict__ dst,
                            const int* __restrict__ off, int* __restrict__ cnt,
                            int* __restrict__ csr_src, int E) {
    int e = blockIdx.x * blockDim.x + threadIdx.x;
    if (e < E) {
        int d = dst[e];
        int p = atomicSub(&cnt[d], 1) - 1;       // slot in [0, deg)
        csr_src[off[d] + p] = src[e];
    }
}

// ---------------- mean aggregation: one wave per node, shuffle-broadcast idx ----
// 8 independent 512B row-gathers in flight per wave for latency hiding.
__global__ __launch_bounds__(256) void agg_kernel(
        const float* __restrict__ x, const int* __restrict__ csr_off,
        const int* __restrict__ csr_src, const float* __restrict__ deg_inv,
        float* __restrict__ outbuf, int N) {
    int wid = blockIdx.x * 4 + (threadIdx.x >> 6);
    int lane = threadIdx.x & 63;
    if (wid >= N) return;
    float2 acc = *((const float2*)(x + (size_t)wid * FDIM) + lane);   // self loop
    int beg = csr_off[wid], end = csr_off[wid + 1];
    for (int j = beg; j < end; j += 64) {
        int c = end - j; if (c > 64) c = 64;
        int idx = (lane < c) ? csr_src[j + lane] : 0;   // one coalesced load
        int t = 0;
        for (; t + 8 <= c; t += 8) {                    // 8 independent row-gathers
            float2 v0 = *((const float2*)(x + (size_t)__shfl(idx, t + 0) * FDIM) + lane);
            float2 v1 = *((const float2*)(x + (size_t)__shfl(idx, t + 1) * FDIM) + lane);
            float2 v2 = *((const float2*)(x + (size_t)__shfl(idx, t + 2) * FDIM) + lane);
            float2 v3 = *((const float2*)(x + (size_t)__shfl(idx, t + 3) * FDIM) + lane);
            float2 v4 = *((const float2*)(x + (size_t)__shfl(idx, t + 4) * FDIM) + lane);
            float2 v5 = *((const float2*)(x + (size_t)__shfl(idx, t + 5) * FDIM) + lane);
            float2 v6 = *((const float2*)(x + (size_t)__shfl(idx, t + 6) * FDIM) + lane);
            float2 v7 = *((const float2*)(x + (size_t)__shfl(idx, t + 7) * FDIM) + lane);
            acc.x += v0.x; acc.y += v0.y;  acc.x += v1.x; acc.y += v1.y;
            acc.x += v2.x; acc.y += v2.y;  acc.x += v3.x; acc.y += v3.y;
            acc.x += v4.x; acc.y += v4.y;  acc.x += v5.x; acc.y += v5.y;
            acc.x += v6.x; acc.y += v6.y;  acc.x += v7.x; acc.y += v7.y;
        }
        for (; t + 4 <= c; t += 4) {
            float2 v0 = *((const float2*)(x + (size_t)__shfl(idx, t + 0) * FDIM) + lane);
            float2 v1 = *((const float2*)(x + (size_t)__shfl(idx, t + 1) * FDIM) + lane);
            float2 v2 = *((const float2*)(x + (size_t)__shfl(idx, t + 2) * FDIM) + lane);
            float2 v3 = *((const float2*)(x + (size_t)__shfl(idx, t + 3) * FDIM) + lane);
            acc.x += v0.x; acc.y += v0.y;  acc.x += v1.x; acc.y += v1.y;
            acc.x += v2.x; acc.y += v2.y;  acc.x += v3.x; acc.y += v3.y;
        }
        for (; t < c; ++t) {
            float2 v = *((const float2*)(x + (size_t)__shfl(idx, t) * FDIM) + lane);
            acc.x += v.x; acc.y += v.y;
        }
    }
    float di = deg_inv[wid];
    float2 r; r.x = acc.x * di; r.y = acc.y * di;
    *((float2*)(outbuf + (size_t)wid * FDIM) + lane) = r;
}

// ---------------- GEMM1: h1 = leaky([feat|agg] @ [W1s;W1n] + b1) ----------------
// 128x128 tile, BK=32, 256 threads, 8x8/thread with STRIDED row/col assignment:
// rows ty+16i, cols tx+16j -> all k-loop LDS reads are conflict-free broadcasts.
__global__ __launch_bounds__(256) void gemm1_kernel(
        const float* __restrict__ feat, const float* __restrict__ agg,
        const float* __restrict__ Wself, const float* __restrict__ Wneigh,
        const float* __restrict__ bias, float* __restrict__ h1, int M) {
    __shared__ float As[128][36];    // [row][k]  pitch 36: bank = 4*row + k
    __shared__ float Ws[32][132];    // [k][col]  pitch 132: bank = 4*k + col
    int tid = threadIdx.x;
    int tx = tid & 15;               // cols tx + 16j
    int ty = tid >> 4;               // rows ty + 16i
    int row0 = blockIdx.x * 128;
    float acc[8][8];
#pragma unroll
    for (int i = 0; i < 8; ++i)
#pragma unroll
        for (int j = 0; j < 8; ++j) acc[i][j] = 0.f;

    for (int chunk = 0; chunk < 8; ++chunk) {
        const float* Asrc = (chunk < 4) ? feat : agg;
        const float* Wsrc = (chunk < 4) ? Wself : Wneigh;
        int kb = (chunk & 3) << 5;
        // A tile: 128 rows x 32 k. thread: row tid>>1, 16 floats at (tid&1)*16.
        {
            int r = tid >> 1;
            int c0 = (tid & 1) << 4;
            int gr = row0 + r;
            const float* sp = Asrc + (size_t)gr * FDIM + kb + c0;
#pragma unroll
            for (int i = 0; i < 4; ++i) {
                float4 v = (gr < M) ? *(const float4*)(sp + (i << 2))
                                    : make_float4(0.f, 0.f, 0.f, 0.f);
                *(float4*)&As[r][c0 + (i << 2)] = v;
            }
        }
        // W tile: 32 k-rows x 128 cols. thread: k-row tid>>3, 16 floats.
        {
            int kr = tid >> 3;
            int c0 = (tid & 7) << 4;
            const float* sp = Wsrc + (size_t)(kb + kr) * FDIM + c0;
#pragma unroll
            for (int i = 0; i < 4; ++i)
                *(float4*)&Ws[kr][c0 + (i << 2)] = *(const float4*)(sp + (i << 2));
        }
        __syncthreads();
#pragma unroll 4
        for (int k = 0; k < 32; ++k) {
            float a[8], w[8];
#pragma unroll
            for (int i = 0; i < 8; ++i) a[i] = As[ty + (i << 4)][k];   // 4 banks, bcast16
#pragma unroll
            for (int j = 0; j < 8; ++j) w[j] = Ws[k][tx + (j << 4)];   // 16 banks, bcast4
#pragma unroll
            for (int i = 0; i < 8; ++i)
#pragma unroll
                for (int j = 0; j < 8; ++j)
                    acc[i][j] = fmaf(a[i], w[j], acc[i][j]);
        }
        __syncthreads();
    }
    float bcol[8];
#pragma unroll
    for (int j = 0; j < 8; ++j) bcol[j] = bias[tx + (j << 4)];
#pragma unroll
    for (int i = 0; i < 8; ++i) {
        int gr = row0 + ty + (i << 4);
        if (gr < M) {
            float* dp = h1 + (size_t)gr * FDIM + tx;
#pragma unroll
            for (int j = 0; j < 8; ++j) {
                float v = acc[i][j] + bcol[j];
                dp[j << 4] = (v >= 0.f) ? v : 0.01f * v;
            }
        }
    }
}

// ---------------- fold layer-2 weights through the score layer ----------------
__global__ void wfuse_kernel(const float* __restrict__ W2s, const float* __restrict__ W2n,
                             const float* __restrict__ b2, const float* __restrict__ Wsc,
                             const float* __restrict__ bsc,
                             float* __restrict__ Wf, float* __restrict__ bf) {
    int gid = blockIdx.x * blockDim.x + threadIdx.x;
    if (gid < 256 * NCLS) {
        int r = gid / NCLS, c = gid % NCLS;
        const float* wrow = (r < 128) ? (W2s + (size_t)r * 128) : (W2n + (size_t)(r - 128) * 128);
        float acc = 0.f;
        for (int k = 0; k < 128; ++k) acc = fmaf(wrow[k], Wsc[k * NCLS + c], acc);
        Wf[gid] = acc;
    } else if (gid < 256 * NCLS + NCLS) {
        int c = gid - 256 * NCLS;
        float acc = bsc[c];
        for (int k = 0; k < 128; ++k) acc = fmaf(b2[k], Wsc[k * NCLS + c], acc);
        bf[c] = acc;
    }
}

// ---------------- GEMM2: out = [h1|agg2] @ Wf + bf ----------------
// 128-row tile, BK=32, 256 threads, 4 rows x 5 cols per thread (strided),
// LDS-staged epilogue for coalesced float4 output stores.
__global__ __launch_bounds__(256) void gemm2_kernel(
        const float* __restrict__ h1, const float* __restrict__ agg,
        const float* __restrict__ Wf, const float* __restrict__ bf,
        float* __restrict__ out, int M) {
    __shared__ float smem[6016];               // As 128*36=4608 | Ws2 32*44=1408
    float (*As)[36]  = (float(*)[36])smem;
    float (*Ws2)[44] = (float(*)[44])(smem + 4608);
    float* Ot = smem;                          // reused for epilogue, 128*40=5120
    int tid = threadIdx.x;
    int tx = tid & 7;                // cols tx + 8j (j<5)
    int ty = tid >> 3;               // rows ty + 32i (i<4)
    int row0 = blockIdx.x * 128;
    float acc[4][5];
#pragma unroll
    for (int i = 0; i < 4; ++i)
#pragma unroll
        for (int j = 0; j < 5; ++j) acc[i][j] = 0.f;

    for (int chunk = 0; chunk < 8; ++chunk) {
        const float* Asrc = (chunk < 4) ? h1 : agg;
        int kb = (chunk & 3) << 5;
        {
            int r = tid >> 1;
            int c0 = (tid & 1) << 4;
            int gr = row0 + r;
            const float* sp = Asrc + (size_t)gr * FDIM + kb + c0;
#pragma unroll
            for (int i = 0; i < 4; ++i) {
                float4 v = (gr < M) ? *(const float4*)(sp + (i << 2))
                                    : make_float4(0.f, 0.f, 0.f, 0.f);
                *(float4*)&As[r][c0 + (i << 2)] = v;
            }
        }
        {
            int base = (((chunk >> 2) << 7) + kb) * NCLS;   // Wf row offset * 40
            for (int idx = tid; idx < 32 * NCLS; idx += 256)
                Ws2[idx / NCLS][idx % NCLS] = Wf[base + idx];
        }
        __syncthreads();
#pragma unroll 4
        for (int k = 0; k < 32; ++k) {
            float a[4], w[5];
#pragma unroll
            for (int i = 0; i < 4; ++i) a[i] = As[ty + (i << 5)][k];   // 8 banks, bcast8
#pragma unroll
            for (int j = 0; j < 5; ++j) w[j] = Ws2[k][tx + (j << 3)];  // 8 banks, bcast8
#pragma unroll
            for (int i = 0; i < 4; ++i)
#pragma unroll
                for (int j = 0; j < 5; ++j)
                    acc[i][j] = fmaf(a[i], w[j], acc[i][j]);
        }
        __syncthreads();
    }
    // epilogue: stage tile in LDS, then coalesced float4 stores
#pragma unroll
    for (int i = 0; i < 4; ++i)
#pragma unroll
        for (int j = 0; j < 5; ++j)
            Ot[(ty + (i << 5)) * NCLS + tx + (j << 3)] = acc[i][j] + bf[tx + (j << 3)];
    __syncthreads();
#pragma unroll
    for (int q = 0; q < 5; ++q) {
        int f4 = tid + (q << 8);          // 1280 float4 = 128*40 floats
        int off = f4 << 2;
        int r = off / NCLS;
        int gr = row0 + r;
        if (gr < M)
            *(float4*)(out + (size_t)gr * NCLS + (off % NCLS)) = *(float4*)(Ot + off);
    }
}

extern "C" void kernel_launch(void* const* d_in, const int* in_sizes, int n_in,
                              void* d_out, int out_size, void* d_ws, size_t ws_size,
                              hipStream_t stream) {
    (void)in_sizes; (void)n_in; (void)out_size; (void)ws_size;
    const float* feat = (const float*)d_in[0];
    const int*   src  = (const int*)d_in[1];
    const int*   dst  = (const int*)d_in[2];
    const float* W1s  = (const float*)d_in[3];
    const float* W1n  = (const float*)d_in[4];
    const float* b1   = (const float*)d_in[5];
    const float* W2s  = (const float*)d_in[6];
    const float* W2n  = (const float*)d_in[7];
    const float* b2   = (const float*)d_in[8];
    const float* Wsc  = (const float*)d_in[9];
    const float* bsc  = (const float*)d_in[10];
    float* out = (float*)d_out;

    // workspace partition (bytes, all 16B-aligned); total ~110.45 MB
    char* ws = (char*)d_ws;
    float* agg     = (float*)(ws + 0);              // N*128 f = 51,200,000 B
    float* h1      = (float*)(ws + 51200000);       // N*128 f
    float* deg_inv = (float*)(ws + 102400000);      // N f
    int*   cnt     = (int*)  (ws + 102800000);      // N i
    int*   excl    = (int*)  (ws + 103200000);      // N i
    int*   csr_off = (int*)  (ws + 103600000);      // N+1 i (pad to 400,128 B)
    int*   csr_src = (int*)  (ws + 104000128);      // E i = 6,400,000 B
    int*   bsum    = (int*)  (ws + 110400128);      // 98 i
    int*   boff    = (int*)  (ws + 110400640);      // 99 i
    float* Wf      = (float*)(ws + 110401664);      // 256*40 f
    float* bf      = (float*)(ws + 110442624);      // 40 f

    hipMemsetAsync(cnt, 0, N_NODES * sizeof(int), stream);

    count_kernel<<<(N_EDGES + 255) / 256, 256, 0, stream>>>(dst, cnt, N_EDGES);
    scan_phase1<<<SCAN_BLOCKS, 1024, 0, stream>>>(cnt, excl, bsum, deg_inv, N_NODES);
    scan_phase2<<<1, 128, 0, stream>>>(bsum, boff, SCAN_BLOCKS);
    scan_phase3<<<SCAN_BLOCKS, 1024, 0, stream>>>(excl, boff, csr_off, N_NODES, SCAN_BLOCKS);
    fill_kernel<<<(N_EDGES + 255) / 256, 256, 0, stream>>>(src, dst, csr_off, cnt, csr_src, N_EDGES);
    wfuse_kernel<<<41, 256, 0, stream>>>(W2s, W2n, b2, Wsc, bsc, Wf, bf);

    // layer 1
    agg_kernel<<<N_NODES / 4, 256, 0, stream>>>(feat, csr_off, csr_src, deg_inv, agg, N_NODES);
    gemm1_kernel<<<(N_NODES + 127) / 128, 256, 0, stream>>>(feat, agg, W1s, W1n, b1, h1, N_NODES);
    // layer 2 + fused score
    agg_kernel<<<N_NODES / 4, 256, 0, stream>>>(h1, csr_off, csr_src, deg_inv, agg, N_NODES);
    gemm2_kernel<<<(N_NODES + 127) / 128, 256, 0, stream>>>(h1, agg, Wf, bf, out, N_NODES);
}

// Round 10
// 584.873 us; speedup vs baseline: 1.1672x; 1.1672x over previous
//
#include <hip/hip_runtime.h>
#include <cstdint>
#include <cstddef>

#define N_NODES 100000
#define N_EDGES 1600000
#define FDIM 128
#define NCLS 40
#define SCAN_BLOCKS 98   // ceil(100000/1024)

// fill partitioning: 8 dst-range classes (intended 1:1 with XCDs via bid%8),
// 256 blocks per class, 6250 edges per block (256*6250 = 1.6M exact).
#define FILL_CLASSES 8
#define FILL_BPC 256
#define FILL_EPB 6250
#define NODES_PER_CLASS (N_NODES / FILL_CLASSES)   // 12500 exact

// ---------------- degree count ----------------
__global__ void count_kernel(const int* __restrict__ dst, int* __restrict__ cnt, int E) {
    int e = blockIdx.x * blockDim.x + threadIdx.x;
    if (e < E) atomicAdd(&cnt[dst[e]], 1);
}

// ---------------- 3-phase exclusive scan over cnt -> csr_off (+ deg_inv) -------
__global__ void scan_phase1(const int* __restrict__ cnt, int* __restrict__ excl,
                            int* __restrict__ bsum, float* __restrict__ deg_inv, int n) {
    __shared__ int lds[1024];
    int tid = threadIdx.x;
    int i = blockIdx.x * 1024 + tid;
    int v = (i < n) ? cnt[i] : 0;
    if (i < n) deg_inv[i] = 1.0f / (float)(v + 1);   // +1 self loop
    lds[tid] = v;
    __syncthreads();
    for (int d = 1; d < 1024; d <<= 1) {
        int t = (tid >= d) ? lds[tid - d] : 0;
        __syncthreads();
        lds[tid] += t;
        __syncthreads();
    }
    if (i < n) excl[i] = lds[tid] - v;
    if (tid == 1023) bsum[blockIdx.x] = lds[1023];
}

__global__ void scan_phase2(const int* __restrict__ bsum, int* __restrict__ boff, int nb) {
    __shared__ int lds[128];
    int tid = threadIdx.x;   // blockDim = 128, nb <= 128
    int v = (tid < nb) ? bsum[tid] : 0;
    lds[tid] = v;
    __syncthreads();
    for (int d = 1; d < 128; d <<= 1) {
        int t = (tid >= d) ? lds[tid - d] : 0;
        __syncthreads();
        lds[tid] += t;
        __syncthreads();
    }
    if (tid < nb) boff[tid] = lds[tid] - v;
    if (tid == 127) boff[nb] = lds[127];   // grand total = E
}

__global__ void scan_phase3(const int* __restrict__ excl, const int* __restrict__ boff,
                            int* __restrict__ off, int n, int nb) {
    int i = blockIdx.x * blockDim.x + threadIdx.x;
    if (i < n) off[i] = excl[i] + boff[i >> 10];
    if (i == 0) off[n] = boff[nb];
}

// fill: XCD-local scatter. Class k (= blockIdx%8) scatters ONLY dst in its
// 12500-node range -> each csr_src cache line written by one XCD's L2 ->
// full-line writebacks instead of 16x partial-line amplification.
__global__ __launch_bounds__(256) void fill_kernel(
        const int* __restrict__ src, const int* __restrict__ dst,
        const int* __restrict__ off, int* __restrict__ cnt,
        int* __restrict__ csr_src, int E) {
    int cls = blockIdx.x & (FILL_CLASSES - 1);
    int w   = blockIdx.x >> 3;
    int lo  = cls * NODES_PER_CLASS;
    int hi  = lo + NODES_PER_CLASS;
    int beg = w * FILL_EPB;
    int end = beg + FILL_EPB; if (end > E) end = E;
    for (int e = beg + threadIdx.x; e < end; e += 256) {
        int d = dst[e];
        if (d >= lo && d < hi) {
            int p = atomicSub(&cnt[d], 1) - 1;       // slot in [0, deg)
            csr_src[off[d] + p] = src[e];
        }
    }
}

// ---------------- mean aggregation (layer 1): one wave per node --------------
__global__ __launch_bounds__(256) void agg_kernel(
        const float* __restrict__ x, const int* __restrict__ csr_off,
        const int* __restrict__ csr_src, const float* __restrict__ deg_inv,
        float* __restrict__ outbuf, int N) {
    int wid = blockIdx.x * 4 + (threadIdx.x >> 6);
    int lane = threadIdx.x & 63;
    if (wid >= N) return;
    float2 acc = *((const float2*)(x + (size_t)wid * FDIM) + lane);   // self loop
    int beg = csr_off[wid], end = csr_off[wid + 1];
    for (int j = beg; j < end; j += 64) {
        int c = end - j; if (c > 64) c = 64;
        int idx = (lane < c) ? csr_src[j + lane] : 0;   // one coalesced load
        int t = 0;
        for (; t + 8 <= c; t += 8) {                    // 8 independent row-gathers
            float2 v0 = *((const float2*)(x + (size_t)__shfl(idx, t + 0) * FDIM) + lane);
            float2 v1 = *((const float2*)(x + (size_t)__shfl(idx, t + 1) * FDIM) + lane);
            float2 v2 = *((const float2*)(x + (size_t)__shfl(idx, t + 2) * FDIM) + lane);
            float2 v3 = *((const float2*)(x + (size_t)__shfl(idx, t + 3) * FDIM) + lane);
            float2 v4 = *((const float2*)(x + (size_t)__shfl(idx, t + 4) * FDIM) + lane);
            float2 v5 = *((const float2*)(x + (size_t)__shfl(idx, t + 5) * FDIM) + lane);
            float2 v6 = *((const float2*)(x + (size_t)__shfl(idx, t + 6) * FDIM) + lane);
            float2 v7 = *((const float2*)(x + (size_t)__shfl(idx, t + 7) * FDIM) + lane);
            acc.x += v0.x; acc.y += v0.y;  acc.x += v1.x; acc.y += v1.y;
            acc.x += v2.x; acc.y += v2.y;  acc.x += v3.x; acc.y += v3.y;
            acc.x += v4.x; acc.y += v4.y;  acc.x += v5.x; acc.y += v5.y;
            acc.x += v6.x; acc.y += v6.y;  acc.x += v7.x; acc.y += v7.y;
        }
        for (; t + 4 <= c; t += 4) {
            float2 v0 = *((const float2*)(x + (size_t)__shfl(idx, t + 0) * FDIM) + lane);
            float2 v1 = *((const float2*)(x + (size_t)__shfl(idx, t + 1) * FDIM) + lane);
            float2 v2 = *((const float2*)(x + (size_t)__shfl(idx, t + 2) * FDIM) + lane);
            float2 v3 = *((const float2*)(x + (size_t)__shfl(idx, t + 3) * FDIM) + lane);
            acc.x += v0.x; acc.y += v0.y;  acc.x += v1.x; acc.y += v1.y;
            acc.x += v2.x; acc.y += v2.y;  acc.x += v3.x; acc.y += v3.y;
        }
        for (; t < c; ++t) {
            float2 v = *((const float2*)(x + (size_t)__shfl(idx, t) * FDIM) + lane);
            acc.x += v.x; acc.y += v.y;
        }
    }
    float di = deg_inv[wid];
    float2 r; r.x = acc.x * di; r.y = acc.y * di;
    *((float2*)(outbuf + (size_t)wid * FDIM) + lane) = r;
}

// ---------------- GEMM1: h1 = leaky([feat|agg] @ [W1s;W1n] + b1) ----------------
__global__ __launch_bounds__(256) void gemm1_kernel(
        const float* __restrict__ feat, const float* __restrict__ agg,
        const float* __restrict__ Wself, const float* __restrict__ Wneigh,
        const float* __restrict__ bias, float* __restrict__ h1, int M) {
    __shared__ float As[128][36];    // [row][k]
    __shared__ float Ws[32][132];    // [k][col]
    int tid = threadIdx.x;
    int tx = tid & 15;               // cols tx + 16j
    int ty = tid >> 4;               // rows ty + 16i
    int row0 = blockIdx.x * 128;
    float acc[8][8];
#pragma unroll
    for (int i = 0; i < 8; ++i)
#pragma unroll
        for (int j = 0; j < 8; ++j) acc[i][j] = 0.f;

    for (int chunk = 0; chunk < 8; ++chunk) {
        const float* Asrc = (chunk < 4) ? feat : agg;
        const float* Wsrc = (chunk < 4) ? Wself : Wneigh;
        int kb = (chunk & 3) << 5;
        {
            int r = tid >> 1;
            int c0 = (tid & 1) << 4;
            int gr = row0 + r;
            const float* sp = Asrc + (size_t)gr * FDIM + kb + c0;
#pragma unroll
            for (int i = 0; i < 4; ++i) {
                float4 v = (gr < M) ? *(const float4*)(sp + (i << 2))
                                    : make_float4(0.f, 0.f, 0.f, 0.f);
                *(float4*)&As[r][c0 + (i << 2)] = v;
            }
        }
        {
            int kr = tid >> 3;
            int c0 = (tid & 7) << 4;
            const float* sp = Wsrc + (size_t)(kb + kr) * FDIM + c0;
#pragma unroll
            for (int i = 0; i < 4; ++i)
                *(float4*)&Ws[kr][c0 + (i << 2)] = *(const float4*)(sp + (i << 2));
        }
        __syncthreads();
#pragma unroll 4
        for (int k = 0; k < 32; ++k) {
            float a[8], w[8];
#pragma unroll
            for (int i = 0; i < 8; ++i) a[i] = As[ty + (i << 4)][k];
#pragma unroll
            for (int j = 0; j < 8; ++j) w[j] = Ws[k][tx + (j << 4)];
#pragma unroll
            for (int i = 0; i < 8; ++i)
#pragma unroll
                for (int j = 0; j < 8; ++j)
                    acc[i][j] = fmaf(a[i], w[j], acc[i][j]);
        }
        __syncthreads();
    }
    float bcol[8];
#pragma unroll
    for (int j = 0; j < 8; ++j) bcol[j] = bias[tx + (j << 4)];
#pragma unroll
    for (int i = 0; i < 8; ++i) {
        int gr = row0 + ty + (i << 4);
        if (gr < M) {
            float* dp = h1 + (size_t)gr * FDIM + tx;
#pragma unroll
            for (int j = 0; j < 8; ++j) {
                float v = acc[i][j] + bcol[j];
                dp[j << 4] = (v >= 0.f) ? v : 0.01f * v;
            }
        }
    }
}

// ---------------- fold layer-2 weights through the score layer ----------------
// Wf[0:128][40] = W2_self@W_score ; Wf[128:256][40] = W2_neigh@W_score
// bf = b2 @ W_score + b_score
__global__ void wfuse_kernel(const float* __restrict__ W2s, const float* __restrict__ W2n,
                             const float* __restrict__ b2, const float* __restrict__ Wsc,
                             const float* __restrict__ bsc,
                             float* __restrict__ Wf, float* __restrict__ bf) {
    int gid = blockIdx.x * blockDim.x + threadIdx.x;
    if (gid < 256 * NCLS) {
        int r = gid / NCLS, c = gid % NCLS;
        const float* wrow = (r < 128) ? (W2s + (size_t)r * 128) : (W2n + (size_t)(r - 128) * 128);
        float acc = 0.f;
        for (int k = 0; k < 128; ++k) acc = fmaf(wrow[k], Wsc[k * NCLS + c], acc);
        Wf[gid] = acc;
    } else if (gid < 256 * NCLS + NCLS) {
        int c = gid - 256 * NCLS;
        float acc = bsc[c];
        for (int k = 0; k < 128; ++k) acc = fmaf(b2[k], Wsc[k * NCLS + c], acc);
        bf[c] = acc;
    }
}

// ---------------- GEMM2p: pp = h1 @ [Ws40 | Wn40]  (N x 80, no bias) ----------
// Proj-then-aggregate: agg(h1)@Wn40 == agg40(h1@Wn40) since agg is linear.
// 128-row tile, K=128 (4 chunks of 32), 4 rows x 10 cols per thread (strided).
__global__ __launch_bounds__(256) void gemm2p_kernel(
        const float* __restrict__ h1, const float* __restrict__ Wf,
        float* __restrict__ pp, int M) {
    __shared__ float As[128][36];
    __shared__ float Ws2[32][84];
    int tid = threadIdx.x;
    int tx = tid & 7;                // cols tx + 8j (j<10)
    int ty = tid >> 3;               // rows ty + 32i (i<4)
    int row0 = blockIdx.x * 128;
    float acc[4][10];
#pragma unroll
    for (int i = 0; i < 4; ++i)
#pragma unroll
        for (int j = 0; j < 10; ++j) acc[i][j] = 0.f;

    for (int chunk = 0; chunk < 4; ++chunk) {
        int kb = chunk << 5;
        {
            int r = tid >> 1;
            int c0 = (tid & 1) << 4;
            int gr = row0 + r;
            const float* sp = h1 + (size_t)gr * FDIM + kb + c0;
#pragma unroll
            for (int i = 0; i < 4; ++i) {
                float4 v = (gr < M) ? *(const float4*)(sp + (i << 2))
                                    : make_float4(0.f, 0.f, 0.f, 0.f);
                *(float4*)&As[r][c0 + (i << 2)] = v;
            }
        }
        {
            // Ws2[k][c]: c<40 -> Wf[(kb+k)*40+c] (self), c>=40 -> Wf[(128+kb+k)*40+c-40]
            for (int idx = tid; idx < 32 * 80; idx += 256) {
                int kr = idx / 80, c = idx % 80;
                float v = (c < NCLS) ? Wf[(kb + kr) * NCLS + c]
                                     : Wf[(128 + kb + kr) * NCLS + (c - NCLS)];
                Ws2[kr][c] = v;
            }
        }
        __syncthreads();
#pragma unroll 4
        for (int k = 0; k < 32; ++k) {
            float a[4], w[10];
#pragma unroll
            for (int i = 0; i < 4; ++i) a[i] = As[ty + (i << 5)][k];   // 8 banks, bcast8
#pragma unroll
            for (int j = 0; j < 10; ++j) w[j] = Ws2[k][tx + (j << 3)]; // 8 banks, bcast8
#pragma unroll
            for (int i = 0; i < 4; ++i)
#pragma unroll
                for (int j = 0; j < 10; ++j)
                    acc[i][j] = fmaf(a[i], w[j], acc[i][j]);
        }
        __syncthreads();
    }
#pragma unroll
    for (int i = 0; i < 4; ++i) {
        int gr = row0 + ty + (i << 5);
        if (gr < M) {
            float* dp = pp + (size_t)gr * 80 + tx;
#pragma unroll
            for (int j = 0; j < 10; ++j)
                dp[j << 3] = acc[i][j];
        }
    }
}

// ---------------- final: out = ps + bf + deg_inv*(pn_self + sum pn_neigh) -----
// One wave per node; lanes 0..39 hold the 40 output cols; gather is 160B/row.
__global__ __launch_bounds__(256) void final_kernel(
        const float* __restrict__ pp, const int* __restrict__ csr_off,
        const int* __restrict__ csr_src, const float* __restrict__ deg_inv,
        const float* __restrict__ bf, float* __restrict__ out, int N) {
    int wid = blockIdx.x * 4 + (threadIdx.x >> 6);
    int lane = threadIdx.x & 63;
    if (wid >= N) return;
    bool act = (lane < NCLS);
    int ln = act ? lane : 0;
    float accv = act ? pp[(size_t)wid * 80 + NCLS + ln] : 0.f;   // pn self
    int beg = csr_off[wid], end = csr_off[wid + 1];
    for (int j = beg; j < end; j += 64) {
        int c = end - j; if (c > 64) c = 64;
        int idx = (lane < c) ? csr_src[j + lane] : 0;
        int t = 0;
        for (; t + 8 <= c; t += 8) {
            float v0 = pp[(size_t)__shfl(idx, t + 0) * 80 + NCLS + ln];
            float v1 = pp[(size_t)__shfl(idx, t + 1) * 80 + NCLS + ln];
            float v2 = pp[(size_t)__shfl(idx, t + 2) * 80 + NCLS + ln];
            float v3 = pp[(size_t)__shfl(idx, t + 3) * 80 + NCLS + ln];
            float v4 = pp[(size_t)__shfl(idx, t + 4) * 80 + NCLS + ln];
            float v5 = pp[(size_t)__shfl(idx, t + 5) * 80 + NCLS + ln];
            float v6 = pp[(size_t)__shfl(idx, t + 6) * 80 + NCLS + ln];
            float v7 = pp[(size_t)__shfl(idx, t + 7) * 80 + NCLS + ln];
            accv += v0 + v1 + v2 + v3 + v4 + v5 + v6 + v7;
        }
        for (; t + 4 <= c; t += 4) {
            float v0 = pp[(size_t)__shfl(idx, t + 0) * 80 + NCLS + ln];
            float v1 = pp[(size_t)__shfl(idx, t + 1) * 80 + NCLS + ln];
            float v2 = pp[(size_t)__shfl(idx, t + 2) * 80 + NCLS + ln];
            float v3 = pp[(size_t)__shfl(idx, t + 3) * 80 + NCLS + ln];
            accv += v0 + v1 + v2 + v3;
        }
        for (; t < c; ++t)
            accv += pp[(size_t)__shfl(idx, t) * 80 + NCLS + ln];
    }
    if (act)
        out[(size_t)wid * NCLS + ln] = pp[(size_t)wid * 80 + ln] + bf[ln]
                                       + deg_inv[wid] * accv;
}

extern "C" void kernel_launch(void* const* d_in, const int* in_sizes, int n_in,
                              void* d_out, int out_size, void* d_ws, size_t ws_size,
                              hipStream_t stream) {
    (void)in_sizes; (void)n_in; (void)out_size; (void)ws_size;
    const float* feat = (const float*)d_in[0];
    const int*   src  = (const int*)d_in[1];
    const int*   dst  = (const int*)d_in[2];
    const float* W1s  = (const float*)d_in[3];
    const float* W1n  = (const float*)d_in[4];
    const float* b1   = (const float*)d_in[5];
    const float* W2s  = (const float*)d_in[6];
    const float* W2n  = (const float*)d_in[7];
    const float* b2   = (const float*)d_in[8];
    const float* Wsc  = (const float*)d_in[9];
    const float* bsc  = (const float*)d_in[10];
    float* out = (float*)d_out;

    // workspace partition (bytes, all 16B-aligned); total ~110.45 MB
    char* ws = (char*)d_ws;
    float* agg     = (float*)(ws + 0);              // N*128 f (layer1 agg; reused as pp N*80)
    float* h1      = (float*)(ws + 51200000);       // N*128 f
    float* deg_inv = (float*)(ws + 102400000);      // N f
    int*   cnt     = (int*)  (ws + 102800000);      // N i
    int*   excl    = (int*)  (ws + 103200000);      // N i
    int*   csr_off = (int*)  (ws + 103600000);      // N+1 i
    int*   csr_src = (int*)  (ws + 104000128);      // E i
    int*   bsum    = (int*)  (ws + 110400128);      // 98 i
    int*   boff    = (int*)  (ws + 110400640);      // 99 i
    float* Wf      = (float*)(ws + 110401664);      // 256*40 f
    float* bf      = (float*)(ws + 110442624);      // 40 f
    float* pp      = agg;                           // N*80 f = 32 MB, reuses agg slot

    hipMemsetAsync(cnt, 0, N_NODES * sizeof(int), stream);

    count_kernel<<<(N_EDGES + 255) / 256, 256, 0, stream>>>(dst, cnt, N_EDGES);
    scan_phase1<<<SCAN_BLOCKS, 1024, 0, stream>>>(cnt, excl, bsum, deg_inv, N_NODES);
    scan_phase2<<<1, 128, 0, stream>>>(bsum, boff, SCAN_BLOCKS);
    scan_phase3<<<SCAN_BLOCKS, 1024, 0, stream>>>(excl, boff, csr_off, N_NODES, SCAN_BLOCKS);
    fill_kernel<<<FILL_CLASSES * FILL_BPC, 256, 0, stream>>>(src, dst, csr_off, cnt, csr_src, N_EDGES);
    wfuse_kernel<<<41, 256, 0, stream>>>(W2s, W2n, b2, Wsc, bsc, Wf, bf);

    // layer 1
    agg_kernel<<<N_NODES / 4, 256, 0, stream>>>(feat, csr_off, csr_src, deg_inv, agg, N_NODES);
    gemm1_kernel<<<(N_NODES + 127) / 128, 256, 0, stream>>>(feat, agg, W1s, W1n, b1, h1, N_NODES);
    // layer 2 + score, proj-then-aggregate (pp overwrites agg - no longer needed)
    gemm2p_kernel<<<(N_NODES + 127) / 128, 256, 0, stream>>>(h1, Wf, pp, N_NODES);
    final_kernel<<<N_NODES / 4, 256, 0, stream>>>(pp, csr_off, csr_src, deg_inv, bf, out, N_NODES);
}

// Round 12
// 577.436 us; speedup vs baseline: 1.1822x; 1.0129x over previous
//
#include <hip/hip_runtime.h>
#include <cstdint>
#include <cstddef>

#define N_NODES 100000
#define N_EDGES 1600000
#define FDIM 128
#define NCLS 40
#define SCAN_BLOCKS 98   // ceil(100000/1024)

#define FILL_CLASSES 8
#define FILL_BPC 256
#define FILL_EPB 6250
#define NODES_PER_CLASS (N_NODES / FILL_CLASSES)   // 12500 exact

// ---------------- degree count ----------------
__global__ void count_kernel(const int* __restrict__ dst, int* __restrict__ cnt, int E) {
    int e = blockIdx.x * blockDim.x + threadIdx.x;
    if (e < E) atomicAdd(&cnt[dst[e]], 1);
}

// ---------------- 3-phase exclusive scan over cnt -> csr_off (+ deg_inv) -------
__global__ void scan_phase1(const int* __restrict__ cnt, int* __restrict__ excl,
                            int* __restrict__ bsum, float* __restrict__ deg_inv, int n) {
    __shared__ int lds[1024];
    int tid = threadIdx.x;
    int i = blockIdx.x * 1024 + tid;
    int v = (i < n) ? cnt[i] : 0;
    if (i < n) deg_inv[i] = 1.0f / (float)(v + 1);   // +1 self loop
    lds[tid] = v;
    __syncthreads();
    for (int d = 1; d < 1024; d <<= 1) {
        int t = (tid >= d) ? lds[tid - d] : 0;
        __syncthreads();
        lds[tid] += t;
        __syncthreads();
    }
    if (i < n) excl[i] = lds[tid] - v;
    if (tid == 1023) bsum[blockIdx.x] = lds[1023];
}

__global__ void scan_phase2(const int* __restrict__ bsum, int* __restrict__ boff, int nb) {
    __shared__ int lds[128];
    int tid = threadIdx.x;
    int v = (tid < nb) ? bsum[tid] : 0;
    lds[tid] = v;
    __syncthreads();
    for (int d = 1; d < 128; d <<= 1) {
        int t = (tid >= d) ? lds[tid - d] : 0;
        __syncthreads();
        lds[tid] += t;
        __syncthreads();
    }
    if (tid < nb) boff[tid] = lds[tid] - v;
    if (tid == 127) boff[nb] = lds[127];
}

__global__ void scan_phase3(const int* __restrict__ excl, const int* __restrict__ boff,
                            int* __restrict__ off, int n, int nb) {
    int i = blockIdx.x * blockDim.x + threadIdx.x;
    if (i < n) off[i] = excl[i] + boff[i >> 10];
    if (i == 0) off[n] = boff[nb];
}

// fill: XCD-local scatter (class = bid%8 owns one 12500-node dst range).
__global__ __launch_bounds__(256) void fill_kernel(
        const int* __restrict__ src, const int* __restrict__ dst,
        const int* __restrict__ off, int* __restrict__ cnt,
        int* __restrict__ csr_src, int E) {
    int cls = blockIdx.x & (FILL_CLASSES - 1);
    int w   = blockIdx.x >> 3;
    int lo  = cls * NODES_PER_CLASS;
    int hi  = lo + NODES_PER_CLASS;
    int beg = w * FILL_EPB;
    int end = beg + FILL_EPB; if (end > E) end = E;
    for (int e = beg + threadIdx.x; e < end; e += 256) {
        int d = dst[e];
        if (d >= lo && d < hi) {
            int p = atomicSub(&cnt[d], 1) - 1;
            csr_src[off[d] + p] = src[e];
        }
    }
}

// ---------------- mean aggregation (layer 1): one wave per node --------------
// 16 independent 512B row-gathers in flight per wave for latency hiding.
__global__ __launch_bounds__(256) void agg_kernel(
        const float* __restrict__ x, const int* __restrict__ csr_off,
        const int* __restrict__ csr_src, const float* __restrict__ deg_inv,
        float* __restrict__ outbuf, int N) {
    int wid = blockIdx.x * 4 + (threadIdx.x >> 6);
    int lane = threadIdx.x & 63;
    if (wid >= N) return;
    float2 acc = *((const float2*)(x + (size_t)wid * FDIM) + lane);   // self loop
    int beg = csr_off[wid], end = csr_off[wid + 1];
    for (int j = beg; j < end; j += 64) {
        int c = end - j; if (c > 64) c = 64;
        int idx = (lane < c) ? csr_src[j + lane] : 0;   // one coalesced load
        int t = 0;
        for (; t + 16 <= c; t += 16) {                  // 16 independent row-gathers
            float2 v[16];
#pragma unroll
            for (int u = 0; u < 16; ++u)
                v[u] = *((const float2*)(x + (size_t)__shfl(idx, t + u) * FDIM) + lane);
#pragma unroll
            for (int u = 0; u < 16; ++u) { acc.x += v[u].x; acc.y += v[u].y; }
        }
        for (; t + 4 <= c; t += 4) {
            float2 v[4];
#pragma unroll
            for (int u = 0; u < 4; ++u)
                v[u] = *((const float2*)(x + (size_t)__shfl(idx, t + u) * FDIM) + lane);
#pragma unroll
            for (int u = 0; u < 4; ++u) { acc.x += v[u].x; acc.y += v[u].y; }
        }
        for (; t < c; ++t) {
            float2 v = *((const float2*)(x + (size_t)__shfl(idx, t) * FDIM) + lane);
            acc.x += v.x; acc.y += v.y;
        }
    }
    float di = deg_inv[wid];
    float2 r; r.x = acc.x * di; r.y = acc.y * di;
    *((float2*)(outbuf + (size_t)wid * FDIM) + lane) = r;
}

// ---------------- GEMM1: h1 = leaky([feat|agg] @ [W1s;W1n] + b1) ----------------
// 128x128 tile, BK=32, 256 threads, 8x8/thread CONTIGUOUS rows/cols.
// A transposed in LDS [k][row] (2-way write alias = free), k-loop = 4x ds_read_b128
// (~62 cyc incl. 4-way on W) vs 128 cyc FMA -> VALU-bound.
__global__ __launch_bounds__(256) void gemm1_kernel(
        const float* __restrict__ feat, const float* __restrict__ agg,
        const float* __restrict__ Wself, const float* __restrict__ Wneigh,
        const float* __restrict__ bias, float* __restrict__ h1, int M) {
    __shared__ float At[32][132];    // [k][row], pitch 132 (528B, 16B-aligned)
    __shared__ float Ws[32][132];    // [k][col]
    int tid = threadIdx.x;
    int tx = tid & 15;               // cols tx*8 .. +7
    int ty = tid >> 4;               // rows ty*8 .. +7
    int row0 = blockIdx.x * 128;
    float acc[8][8];
#pragma unroll
    for (int i = 0; i < 8; ++i)
#pragma unroll
        for (int j = 0; j < 8; ++j) acc[i][j] = 0.f;

    for (int chunk = 0; chunk < 8; ++chunk) {
        const float* Asrc = (chunk < 4) ? feat : agg;
        const float* Wsrc = (chunk < 4) ? Wself : Wneigh;
        int kb = (chunk & 3) << 5;
        // A tile: 128 rows x 32 k -> TRANSPOSED store (even lanes cover all 32
        // banks; odd lanes alias them 2-way = free per m136).
        {
            int r = tid >> 1;            // 0..127
            int c0 = (tid & 1) << 4;     // 0 or 16
            int gr = row0 + r;
            const float* sp = Asrc + (size_t)gr * FDIM + kb + c0;
#pragma unroll
            for (int i = 0; i < 4; ++i) {
                float4 v = (gr < M) ? *(const float4*)(sp + (i << 2))
                                    : make_float4(0.f, 0.f, 0.f, 0.f);
                At[c0 + (i << 2) + 0][r] = v.x;
                At[c0 + (i << 2) + 1][r] = v.y;
                At[c0 + (i << 2) + 2][r] = v.z;
                At[c0 + (i << 2) + 3][r] = v.w;
            }
        }
        // W tile: 32 k-rows x 128 cols (row-major b128 writes).
        {
            int kr = tid >> 3;
            int c0 = (tid & 7) << 4;
            const float* sp = Wsrc + (size_t)(kb + kr) * FDIM + c0;
#pragma unroll
            for (int i = 0; i < 4; ++i)
                *(float4*)&Ws[kr][c0 + (i << 2)] = *(const float4*)(sp + (i << 2));
        }
        __syncthreads();
#pragma unroll 2
        for (int k = 0; k < 32; ++k) {
            float a[8], w[8];
            *(float4*)&a[0] = *(const float4*)&At[k][ty << 3];
            *(float4*)&a[4] = *(const float4*)&At[k][(ty << 3) + 4];
            *(float4*)&w[0] = *(const float4*)&Ws[k][tx << 3];
            *(float4*)&w[4] = *(const float4*)&Ws[k][(tx << 3) + 4];
#pragma unroll
            for (int i = 0; i < 8; ++i)
#pragma unroll
                for (int j = 0; j < 8; ++j)
                    acc[i][j] = fmaf(a[i], w[j], acc[i][j]);
        }
        __syncthreads();
    }
    float bcol[8];
    *(float4*)&bcol[0] = *(const float4*)&bias[tx << 3];
    *(float4*)&bcol[4] = *(const float4*)&bias[(tx << 3) + 4];
#pragma unroll
    for (int i = 0; i < 8; ++i) {
        int gr = row0 + (ty << 3) + i;
        if (gr < M) {
            float o[8];
#pragma unroll
            for (int j = 0; j < 8; ++j) {
                float v = acc[i][j] + bcol[j];
                o[j] = (v >= 0.f) ? v : 0.01f * v;
            }
            float4* dp = (float4*)(h1 + (size_t)gr * FDIM + (tx << 3));
            dp[0] = make_float4(o[0], o[1], o[2], o[3]);
            dp[1] = make_float4(o[4], o[5], o[6], o[7]);
        }
    }
}

// ---------------- fold layer-2 weights through the score layer ----------------
__global__ void wfuse_kernel(const float* __restrict__ W2s, const float* __restrict__ W2n,
                             const float* __restrict__ b2, const float* __restrict__ Wsc,
                             const float* __restrict__ bsc,
                             float* __restrict__ Wf, float* __restrict__ bf) {
    int gid = blockIdx.x * blockDim.x + threadIdx.x;
    if (gid < 256 * NCLS) {
        int r = gid / NCLS, c = gid % NCLS;
        const float* wrow = (r < 128) ? (W2s + (size_t)r * 128) : (W2n + (size_t)(r - 128) * 128);
        float acc = 0.f;
        for (int k = 0; k < 128; ++k) acc = fmaf(wrow[k], Wsc[k * NCLS + c], acc);
        Wf[gid] = acc;
    } else if (gid < 256 * NCLS + NCLS) {
        int c = gid - 256 * NCLS;
        float acc = bsc[c];
        for (int k = 0; k < 128; ++k) acc = fmaf(b2[k], Wsc[k * NCLS + c], acc);
        bf[c] = acc;
    }
}

// ---------------- GEMM2p: pp = h1 @ [Ws40 | Wn40]  (N x 80, no bias) ----------
__global__ __launch_bounds__(256) void gemm2p_kernel(
        const float* __restrict__ h1, const float* __restrict__ Wf,
        float* __restrict__ pp, int M) {
    __shared__ float As[128][36];
    __shared__ float Ws2[32][84];
    int tid = threadIdx.x;
    int tx = tid & 7;                // cols tx + 8j (j<10)
    int ty = tid >> 3;               // rows ty + 32i (i<4)
    int row0 = blockIdx.x * 128;
    float acc[4][10];
#pragma unroll
    for (int i = 0; i < 4; ++i)
#pragma unroll
        for (int j = 0; j < 10; ++j) acc[i][j] = 0.f;

    for (int chunk = 0; chunk < 4; ++chunk) {
        int kb = chunk << 5;
        {
            int r = tid >> 1;
            int c0 = (tid & 1) << 4;
            int gr = row0 + r;
            const float* sp = h1 + (size_t)gr * FDIM + kb + c0;
#pragma unroll
            for (int i = 0; i < 4; ++i) {
                float4 v = (gr < M) ? *(const float4*)(sp + (i << 2))
                                    : make_float4(0.f, 0.f, 0.f, 0.f);
                *(float4*)&As[r][c0 + (i << 2)] = v;
            }
        }
        {
            for (int idx = tid; idx < 32 * 80; idx += 256) {
                int kr = idx / 80, c = idx % 80;
                float v = (c < NCLS) ? Wf[(kb + kr) * NCLS + c]
                                     : Wf[(128 + kb + kr) * NCLS + (c - NCLS)];
                Ws2[kr][c] = v;
            }
        }
        __syncthreads();
#pragma unroll 4
        for (int k = 0; k < 32; ++k) {
            float a[4], w[10];
#pragma unroll
            for (int i = 0; i < 4; ++i) a[i] = As[ty + (i << 5)][k];
#pragma unroll
            for (int j = 0; j < 10; ++j) w[j] = Ws2[k][tx + (j << 3)];
#pragma unroll
            for (int i = 0; i < 4; ++i)
#pragma unroll
                for (int j = 0; j < 10; ++j)
                    acc[i][j] = fmaf(a[i], w[j], acc[i][j]);
        }
        __syncthreads();
    }
#pragma unroll
    for (int i = 0; i < 4; ++i) {
        int gr = row0 + ty + (i << 5);
        if (gr < M) {
            float* dp = pp + (size_t)gr * 80 + tx;
#pragma unroll
            for (int j = 0; j < 10; ++j)
                dp[j << 3] = acc[i][j];
        }
    }
}

// ---------------- final: out = ps + bf + deg_inv*(pn_self + sum pn_neigh) -----
// 16-deep independent gathers (same MLP treatment as agg).
__global__ __launch_bounds__(256) void final_kernel(
        const float* __restrict__ pp, const int* __restrict__ csr_off,
        const int* __restrict__ csr_src, const float* __restrict__ deg_inv,
        const float* __restrict__ bf, float* __restrict__ out, int N) {
    int wid = blockIdx.x * 4 + (threadIdx.x >> 6);
    int lane = threadIdx.x & 63;
    if (wid >= N) return;
    bool act = (lane < NCLS);
    int ln = act ? lane : 0;
    float accv = act ? pp[(size_t)wid * 80 + NCLS + ln] : 0.f;   // pn self
    int beg = csr_off[wid], end = csr_off[wid + 1];
    for (int j = beg; j < end; j += 64) {
        int c = end - j; if (c > 64) c = 64;
        int idx = (lane < c) ? csr_src[j + lane] : 0;
        int t = 0;
        for (; t + 16 <= c; t += 16) {
            float v[16];
#pragma unroll
            for (int u = 0; u < 16; ++u)
                v[u] = pp[(size_t)__shfl(idx, t + u) * 80 + NCLS + ln];
#pragma unroll
            for (int u = 0; u < 16; ++u) accv += v[u];
        }
        for (; t + 4 <= c; t += 4) {
            float v[4];
#pragma unroll
            for (int u = 0; u < 4; ++u)
                v[u] = pp[(size_t)__shfl(idx, t + u) * 80 + NCLS + ln];
#pragma unroll
            for (int u = 0; u < 4; ++u) accv += v[u];
        }
        for (; t < c; ++t)
            accv += pp[(size_t)__shfl(idx, t) * 80 + NCLS + ln];
    }
    if (act)
        out[(size_t)wid * NCLS + ln] = pp[(size_t)wid * 80 + ln] + bf[ln]
                                       + deg_inv[wid] * accv;
}

extern "C" void kernel_launch(void* const* d_in, const int* in_sizes, int n_in,
                              void* d_out, int out_size, void* d_ws, size_t ws_size,
                              hipStream_t stream) {
    (void)in_sizes; (void)n_in; (void)out_size; (void)ws_size;
    const float* feat = (const float*)d_in[0];
    const int*   src  = (const int*)d_in[1];
    const int*   dst  = (const int*)d_in[2];
    const float* W1s  = (const float*)d_in[3];
    const float* W1n  = (const float*)d_in[4];
    const float* b1   = (const float*)d_in[5];
    const float* W2s  = (const float*)d_in[6];
    const float* W2n  = (const float*)d_in[7];
    const float* b2   = (const float*)d_in[8];
    const float* Wsc  = (const float*)d_in[9];
    const float* bsc  = (const float*)d_in[10];
    float* out = (float*)d_out;

    char* ws = (char*)d_ws;
    float* agg     = (float*)(ws + 0);              // N*128 f (reused as pp N*80)
    float* h1      = (float*)(ws + 51200000);       // N*128 f
    float* deg_inv = (float*)(ws + 102400000);      // N f
    int*   cnt     = (int*)  (ws + 102800000);      // N i
    int*   excl    = (int*)  (ws + 103200000);      // N i
    int*   csr_off = (int*)  (ws + 103600000);      // N+1 i
    int*   csr_src = (int*)  (ws + 104000128);      // E i
    int*   bsum    = (int*)  (ws + 110400128);      // 98 i
    int*   boff    = (int*)  (ws + 110400640);      // 99 i
    float* Wf      = (float*)(ws + 110401664);      // 256*40 f
    float* bf      = (float*)(ws + 110442624);      // 40 f
    float* pp      = agg;

    hipMemsetAsync(cnt, 0, N_NODES * sizeof(int), stream);

    count_kernel<<<(N_EDGES + 255) / 256, 256, 0, stream>>>(dst, cnt, N_EDGES);
    scan_phase1<<<SCAN_BLOCKS, 1024, 0, stream>>>(cnt, excl, bsum, deg_inv, N_NODES);
    scan_phase2<<<1, 128, 0, stream>>>(bsum, boff, SCAN_BLOCKS);
    scan_phase3<<<SCAN_BLOCKS, 1024, 0, stream>>>(excl, boff, csr_off, N_NODES, SCAN_BLOCKS);
    fill_kernel<<<FILL_CLASSES * FILL_BPC, 256, 0, stream>>>(src, dst, csr_off, cnt, csr_src, N_EDGES);
    wfuse_kernel<<<41, 256, 0, stream>>>(W2s, W2n, b2, Wsc, bsc, Wf, bf);

    // layer 1
    agg_kernel<<<N_NODES / 4, 256, 0, stream>>>(feat, csr_off, csr_src, deg_inv, agg, N_NODES);
    gemm1_kernel<<<(N_NODES + 127) / 128, 256, 0, stream>>>(feat, agg, W1s, W1n, b1, h1, N_NODES);
    // layer 2 + score, proj-then-aggregate
    gemm2p_kernel<<<(N_NODES + 127) / 128, 256, 0, stream>>>(h1, Wf, pp, N_NODES);
    final_kernel<<<N_NODES / 4, 256, 0, stream>>>(pp, csr_off, csr_src, deg_inv, bf, out, N_NODES);
}

// Round 14
// 531.475 us; speedup vs baseline: 1.2844x; 1.0865x over previous
//
#include <hip/hip_runtime.h>
#include <hip/hip_fp16.h>
#include <cstdint>
#include <cstddef>

#define N_NODES 100000
#define N_EDGES 1600000
#define FDIM 128
#define NCLS 40
#define SCAN_BLOCKS 98   // ceil(100000/1024)

#define FILL_CLASSES 8
#define FILL_BPC 256
#define FILL_EPB 6250
#define NODES_PER_CLASS (N_NODES / FILL_CLASSES)   // 12500 exact

// ---------------- degree count ----------------
__global__ void count_kernel(const int* __restrict__ dst, int* __restrict__ cnt, int E) {
    int e = blockIdx.x * blockDim.x + threadIdx.x;
    if (e < E) atomicAdd(&cnt[dst[e]], 1);
}

// ---------------- feat -> fp16 table (8 elems/thread) ----------------
__global__ __launch_bounds__(256) void feat16_kernel(
        const float* __restrict__ feat, __half* __restrict__ feat16, int total8) {
    int i = blockIdx.x * blockDim.x + threadIdx.x;
    if (i < total8) {
        const float* sp = feat + (size_t)i * 8;
        float4 a = *(const float4*)sp;
        float4 b = *(const float4*)(sp + 4);
        __half h[8];
        h[0] = __float2half_rn(a.x); h[1] = __float2half_rn(a.y);
        h[2] = __float2half_rn(a.z); h[3] = __float2half_rn(a.w);
        h[4] = __float2half_rn(b.x); h[5] = __float2half_rn(b.y);
        h[6] = __float2half_rn(b.z); h[7] = __float2half_rn(b.w);
        *(uint4*)(feat16 + (size_t)i * 8) = *(uint4*)h;
    }
}

// ---------------- 3-phase exclusive scan over cnt -> csr_off (+ deg_inv) -------
__global__ void scan_phase1(const int* __restrict__ cnt, int* __restrict__ excl,
                            int* __restrict__ bsum, float* __restrict__ deg_inv, int n) {
    __shared__ int lds[1024];
    int tid = threadIdx.x;
    int i = blockIdx.x * 1024 + tid;
    int v = (i < n) ? cnt[i] : 0;
    if (i < n) deg_inv[i] = 1.0f / (float)(v + 1);   // +1 self loop
    lds[tid] = v;
    __syncthreads();
    for (int d = 1; d < 1024; d <<= 1) {
        int t = (tid >= d) ? lds[tid - d] : 0;
        __syncthreads();
        lds[tid] += t;
        __syncthreads();
    }
    if (i < n) excl[i] = lds[tid] - v;
    if (tid == 1023) bsum[blockIdx.x] = lds[1023];
}

__global__ void scan_phase2(const int* __restrict__ bsum, int* __restrict__ boff, int nb) {
    __shared__ int lds[128];
    int tid = threadIdx.x;
    int v = (tid < nb) ? bsum[tid] : 0;
    lds[tid] = v;
    __syncthreads();
    for (int d = 1; d < 128; d <<= 1) {
        int t = (tid >= d) ? lds[tid - d] : 0;
        __syncthreads();
        lds[tid] += t;
        __syncthreads();
    }
    if (tid < nb) boff[tid] = lds[tid] - v;
    if (tid == 127) boff[nb] = lds[127];
}

__global__ void scan_phase3(const int* __restrict__ excl, const int* __restrict__ boff,
                            int* __restrict__ off, int n, int nb) {
    int i = blockIdx.x * blockDim.x + threadIdx.x;
    if (i < n) off[i] = excl[i] + boff[i >> 10];
    if (i == 0) off[n] = boff[nb];
}

// fill: XCD-local scatter (class = bid%8 owns one 12500-node dst range).
__global__ __launch_bounds__(256) void fill_kernel(
        const int* __restrict__ src, const int* __restrict__ dst,
        const int* __restrict__ off, int* __restrict__ cnt,
        int* __restrict__ csr_src, int E) {
    int cls = blockIdx.x & (FILL_CLASSES - 1);
    int w   = blockIdx.x >> 3;
    int lo  = cls * NODES_PER_CLASS;
    int hi  = lo + NODES_PER_CLASS;
    int beg = w * FILL_EPB;
    int end = beg + FILL_EPB; if (end > E) end = E;
    for (int e = beg + threadIdx.x; e < end; e += 256) {
        int d = dst[e];
        if (d >= lo && d < hi) {
            int p = atomicSub(&cnt[d], 1) - 1;
            csr_src[off[d] + p] = src[e];
        }
    }
}

// ---------------- mean aggregation (layer 1): one wave per node --------------
// fp16 gather table (256B/row); self term fp32; fp32 accumulate; 16-deep MLP.
__global__ __launch_bounds__(256) void agg_kernel(
        const float* __restrict__ x, const __half* __restrict__ x16,
        const int* __restrict__ csr_off, const int* __restrict__ csr_src,
        const float* __restrict__ deg_inv, float* __restrict__ outbuf, int N) {
    int wid = blockIdx.x * 4 + (threadIdx.x >> 6);
    int lane = threadIdx.x & 63;
    if (wid >= N) return;
    float2 acc = *((const float2*)(x + (size_t)wid * FDIM) + lane);   // self, fp32
    int beg = csr_off[wid], end = csr_off[wid + 1];
    for (int j = beg; j < end; j += 64) {
        int c = end - j; if (c > 64) c = 64;
        int idx = (lane < c) ? csr_src[j + lane] : 0;   // one coalesced load
        int t = 0;
        for (; t + 16 <= c; t += 16) {                  // 16 independent row-gathers
            __half2 v[16];
#pragma unroll
            for (int u = 0; u < 16; ++u)
                v[u] = *((const __half2*)(x16 + (size_t)__shfl(idx, t + u) * FDIM) + lane);
#pragma unroll
            for (int u = 0; u < 16; ++u) {
                float2 f = __half22float2(v[u]);
                acc.x += f.x; acc.y += f.y;
            }
        }
        for (; t + 4 <= c; t += 4) {
            __half2 v[4];
#pragma unroll
            for (int u = 0; u < 4; ++u)
                v[u] = *((const __half2*)(x16 + (size_t)__shfl(idx, t + u) * FDIM) + lane);
#pragma unroll
            for (int u = 0; u < 4; ++u) {
                float2 f = __half22float2(v[u]);
                acc.x += f.x; acc.y += f.y;
            }
        }
        for (; t < c; ++t) {
            float2 f = __half22float2(
                *((const __half2*)(x16 + (size_t)__shfl(idx, t) * FDIM) + lane));
            acc.x += f.x; acc.y += f.y;
        }
    }
    float di = deg_inv[wid];
    float2 r; r.x = acc.x * di; r.y = acc.y * di;
    *((float2*)(outbuf + (size_t)wid * FDIM) + lane) = r;
}

// ---------------- GEMM1: h1 = leaky([feat|agg] @ [W1s;W1n] + b1) ----------------
// 128x128 tile, BK=32, 8x8/thread contiguous, A transposed in LDS.
__global__ __launch_bounds__(256) void gemm1_kernel(
        const float* __restrict__ feat, const float* __restrict__ agg,
        const float* __restrict__ Wself, const float* __restrict__ Wneigh,
        const float* __restrict__ bias, float* __restrict__ h1, int M) {
    __shared__ float At[32][132];    // [k][row]
    __shared__ float Ws[32][132];    // [k][col]
    int tid = threadIdx.x;
    int tx = tid & 15;               // cols tx*8 .. +7
    int ty = tid >> 4;               // rows ty*8 .. +7
    int row0 = blockIdx.x * 128;
    float acc[8][8];
#pragma unroll
    for (int i = 0; i < 8; ++i)
#pragma unroll
        for (int j = 0; j < 8; ++j) acc[i][j] = 0.f;

    for (int chunk = 0; chunk < 8; ++chunk) {
        const float* Asrc = (chunk < 4) ? feat : agg;
        const float* Wsrc = (chunk < 4) ? Wself : Wneigh;
        int kb = (chunk & 3) << 5;
        {
            int r = tid >> 1;            // 0..127
            int c0 = (tid & 1) << 4;     // 0 or 16
            int gr = row0 + r;
            const float* sp = Asrc + (size_t)gr * FDIM + kb + c0;
#pragma unroll
            for (int i = 0; i < 4; ++i) {
                float4 v = (gr < M) ? *(const float4*)(sp + (i << 2))
                                    : make_float4(0.f, 0.f, 0.f, 0.f);
                At[c0 + (i << 2) + 0][r] = v.x;
                At[c0 + (i << 2) + 1][r] = v.y;
                At[c0 + (i << 2) + 2][r] = v.z;
                At[c0 + (i << 2) + 3][r] = v.w;
            }
        }
        {
            int kr = tid >> 3;
            int c0 = (tid & 7) << 4;
            const float* sp = Wsrc + (size_t)(kb + kr) * FDIM + c0;
#pragma unroll
            for (int i = 0; i < 4; ++i)
                *(float4*)&Ws[kr][c0 + (i << 2)] = *(const float4*)(sp + (i << 2));
        }
        __syncthreads();
#pragma unroll 2
        for (int k = 0; k < 32; ++k) {
            float a[8], w[8];
            *(float4*)&a[0] = *(const float4*)&At[k][ty << 3];
            *(float4*)&a[4] = *(const float4*)&At[k][(ty << 3) + 4];
            *(float4*)&w[0] = *(const float4*)&Ws[k][tx << 3];
            *(float4*)&w[4] = *(const float4*)&Ws[k][(tx << 3) + 4];
#pragma unroll
            for (int i = 0; i < 8; ++i)
#pragma unroll
                for (int j = 0; j < 8; ++j)
                    acc[i][j] = fmaf(a[i], w[j], acc[i][j]);
        }
        __syncthreads();
    }
    float bcol[8];
    *(float4*)&bcol[0] = *(const float4*)&bias[tx << 3];
    *(float4*)&bcol[4] = *(const float4*)&bias[(tx << 3) + 4];
#pragma unroll
    for (int i = 0; i < 8; ++i) {
        int gr = row0 + (ty << 3) + i;
        if (gr < M) {
            float o[8];
#pragma unroll
            for (int j = 0; j < 8; ++j) {
                float v = acc[i][j] + bcol[j];
                o[j] = (v >= 0.f) ? v : 0.01f * v;
            }
            float4* dp = (float4*)(h1 + (size_t)gr * FDIM + (tx << 3));
            dp[0] = make_float4(o[0], o[1], o[2], o[3]);
            dp[1] = make_float4(o[4], o[5], o[6], o[7]);
        }
    }
}

// ---------------- fold layer-2 weights through the score layer ----------------
__global__ void wfuse_kernel(const float* __restrict__ W2s, const float* __restrict__ W2n,
                             const float* __restrict__ b2, const float* __restrict__ Wsc,
                             const float* __restrict__ bsc,
                             float* __restrict__ Wf, float* __restrict__ bf) {
    int gid = blockIdx.x * blockDim.x + threadIdx.x;
    if (gid < 256 * NCLS) {
        int r = gid / NCLS, c = gid % NCLS;
        const float* wrow = (r < 128) ? (W2s + (size_t)r * 128) : (W2n + (size_t)(r - 128) * 128);
        float acc = 0.f;
        for (int k = 0; k < 128; ++k) acc = fmaf(wrow[k], Wsc[k * NCLS + c], acc);
        Wf[gid] = acc;
    } else if (gid < 256 * NCLS + NCLS) {
        int c = gid - 256 * NCLS;
        float acc = bsc[c];
        for (int k = 0; k < 128; ++k) acc = fmaf(b2[k], Wsc[k * NCLS + c], acc);
        bf[c] = acc;
    }
}

// ---------------- GEMM2p: ps = h1@Ws40, pn = h1@Wn40 (separate compact bufs) --
__global__ __launch_bounds__(256) void gemm2p_kernel(
        const float* __restrict__ h1, const float* __restrict__ Wf,
        float* __restrict__ ps, float* __restrict__ pn, int M) {
    __shared__ float As[128][36];
    __shared__ float Ws2[32][84];
    int tid = threadIdx.x;
    int tx = tid & 7;                // cols tx + 8j (j<10)
    int ty = tid >> 3;               // rows ty + 32i (i<4)
    int row0 = blockIdx.x * 128;
    float acc[4][10];
#pragma unroll
    for (int i = 0; i < 4; ++i)
#pragma unroll
        for (int j = 0; j < 10; ++j) acc[i][j] = 0.f;

    for (int chunk = 0; chunk < 4; ++chunk) {
        int kb = chunk << 5;
        {
            int r = tid >> 1;
            int c0 = (tid & 1) << 4;
            int gr = row0 + r;
            const float* sp = h1 + (size_t)gr * FDIM + kb + c0;
#pragma unroll
            for (int i = 0; i < 4; ++i) {
                float4 v = (gr < M) ? *(const float4*)(sp + (i << 2))
                                    : make_float4(0.f, 0.f, 0.f, 0.f);
                *(float4*)&As[r][c0 + (i << 2)] = v;
            }
        }
        {
            for (int idx = tid; idx < 32 * 80; idx += 256) {
                int kr = idx / 80, c = idx % 80;
                float v = (c < NCLS) ? Wf[(kb + kr) * NCLS + c]
                                     : Wf[(128 + kb + kr) * NCLS + (c - NCLS)];
                Ws2[kr][c] = v;
            }
        }
        __syncthreads();
#pragma unroll 4
        for (int k = 0; k < 32; ++k) {
            float a[4], w[10];
#pragma unroll
            for (int i = 0; i < 4; ++i) a[i] = As[ty + (i << 5)][k];
#pragma unroll
            for (int j = 0; j < 10; ++j) w[j] = Ws2[k][tx + (j << 3)];
#pragma unroll
            for (int i = 0; i < 4; ++i)
#pragma unroll
                for (int j = 0; j < 10; ++j)
                    acc[i][j] = fmaf(a[i], w[j], acc[i][j]);
        }
        __syncthreads();
    }
#pragma unroll
    for (int i = 0; i < 4; ++i) {
        int gr = row0 + ty + (i << 5);
        if (gr < M) {
#pragma unroll
            for (int j = 0; j < 10; ++j) {
                int cj = tx + (j << 3);
                if (cj < NCLS) ps[(size_t)gr * NCLS + cj] = acc[i][j];
                else           pn[(size_t)gr * NCLS + (cj - NCLS)] = acc[i][j];
            }
        }
    }
}

// ---------------- final: out = ps + bf + deg_inv*(pn_self + sum pn_neigh) -----
__global__ __launch_bounds__(256) void final_kernel(
        const float* __restrict__ ps, const float* __restrict__ pn,
        const int* __restrict__ csr_off, const int* __restrict__ csr_src,
        const float* __restrict__ deg_inv, const float* __restrict__ bf,
        float* __restrict__ out, int N) {
    int wid = blockIdx.x * 4 + (threadIdx.x >> 6);
    int lane = threadIdx.x & 63;
    if (wid >= N) return;
    bool act = (lane < NCLS);
    int ln = act ? lane : 0;
    float accv = act ? pn[(size_t)wid * NCLS + ln] : 0.f;   // pn self
    int beg = csr_off[wid], end = csr_off[wid + 1];
    for (int j = beg; j < end; j += 64) {
        int c = end - j; if (c > 64) c = 64;
        int idx = (lane < c) ? csr_src[j + lane] : 0;
        int t = 0;
        for (; t + 16 <= c; t += 16) {
            float v[16];
#pragma unroll
            for (int u = 0; u < 16; ++u)
                v[u] = pn[(size_t)__shfl(idx, t + u) * NCLS + ln];
#pragma unroll
            for (int u = 0; u < 16; ++u) accv += v[u];
        }
        for (; t + 4 <= c; t += 4) {
            float v[4];
#pragma unroll
            for (int u = 0; u < 4; ++u)
                v[u] = pn[(size_t)__shfl(idx, t + u) * NCLS + ln];
#pragma unroll
            for (int u = 0; u < 4; ++u) accv += v[u];
        }
        for (; t < c; ++t)
            accv += pn[(size_t)__shfl(idx, t) * NCLS + ln];
    }
    if (act)
        out[(size_t)wid * NCLS + ln] = ps[(size_t)wid * NCLS + ln] + bf[ln]
                                       + deg_inv[wid] * accv;
}

extern "C" void kernel_launch(void* const* d_in, const int* in_sizes, int n_in,
                              void* d_out, int out_size, void* d_ws, size_t ws_size,
                              hipStream_t stream) {
    (void)in_sizes; (void)n_in; (void)out_size; (void)ws_size;
    const float* feat = (const float*)d_in[0];
    const int*   src  = (const int*)d_in[1];
    const int*   dst  = (const int*)d_in[2];
    const float* W1s  = (const float*)d_in[3];
    const float* W1n  = (const float*)d_in[4];
    const float* b1   = (const float*)d_in[5];
    const float* W2s  = (const float*)d_in[6];
    const float* W2n  = (const float*)d_in[7];
    const float* b2   = (const float*)d_in[8];
    const float* Wsc  = (const float*)d_in[9];
    const float* bsc  = (const float*)d_in[10];
    float* out = (float*)d_out;

    char* ws = (char*)d_ws;
    float*  agg     = (float*)(ws + 0);             // N*128 f; later ps/pn overlay
    float*  h1      = (float*)(ws + 51200000);      // N*128 f; feat16 overlays pre-gemm1
    float*  deg_inv = (float*)(ws + 102400000);     // N f
    int*    cnt     = (int*)  (ws + 102800000);     // N i
    int*    excl    = (int*)  (ws + 103200000);     // N i
    int*    csr_off = (int*)  (ws + 103600000);     // N+1 i
    int*    csr_src = (int*)  (ws + 104000128);     // E i
    int*    bsum    = (int*)  (ws + 110400128);     // 98 i
    int*    boff    = (int*)  (ws + 110400640);     // 99 i
    float*  Wf      = (float*)(ws + 110401664);     // 256*40 f
    float*  bf      = (float*)(ws + 110442624);     // 40 f
    // overlays (time-disjoint):
    __half* feat16  = (__half*)h1;                  // 25.6 MB, dead once gemm1 writes h1
    float*  ps      = agg;                          // N*40 f, after agg is consumed
    float*  pn      = (float*)(ws + 16000000);      // N*40 f

    hipMemsetAsync(cnt, 0, N_NODES * sizeof(int), stream);

    feat16_kernel<<<(N_NODES * FDIM / 8 + 255) / 256, 256, 0, stream>>>(
        feat, feat16, N_NODES * FDIM / 8);
    count_kernel<<<(N_EDGES + 255) / 256, 256, 0, stream>>>(dst, cnt, N_EDGES);
    scan_phase1<<<SCAN_BLOCKS, 1024, 0, stream>>>(cnt, excl, bsum, deg_inv, N_NODES);
    scan_phase2<<<1, 128, 0, stream>>>(bsum, boff, SCAN_BLOCKS);
    scan_phase3<<<SCAN_BLOCKS, 1024, 0, stream>>>(excl, boff, csr_off, N_NODES, SCAN_BLOCKS);
    fill_kernel<<<FILL_CLASSES * FILL_BPC, 256, 0, stream>>>(src, dst, csr_off, cnt, csr_src, N_EDGES);
    wfuse_kernel<<<41, 256, 0, stream>>>(W2s, W2n, b2, Wsc, bsc, Wf, bf);

    // layer 1
    agg_kernel<<<N_NODES / 4, 256, 0, stream>>>(feat, feat16, csr_off, csr_src,
                                                deg_inv, agg, N_NODES);
    gemm1_kernel<<<(N_NODES + 127) / 128, 256, 0, stream>>>(feat, agg, W1s, W1n, b1, h1, N_NODES);
    // layer 2 + score, proj-then-aggregate (ps/pn overlay agg region - agg dead)
    gemm2p_kernel<<<(N_NODES + 127) / 128, 256, 0, stream>>>(h1, Wf, ps, pn, N_NODES);
    final_kernel<<<N_NODES / 4, 256, 0, stream>>>(ps, pn, csr_off, csr_src,
                                                  deg_inv, bf, out, N_NODES);
}